// Round 1
// baseline (5287.267 us; speedup 1.0000x reference)
//
#include <hip/hip_runtime.h>
#include <math.h>

#define S 2048
#define D 512
#define H 8
#define DH 64
#define F 2048
#define NLAYER 2

#define BM 64
#define BN 64
#define BK 16

// ---------------- positional encoding add ----------------
// PE[s, j]       = sin(s * r_j)   j in [0, 256),  r_j = 10000^(-j/256)
// PE[s, 256 + j] = cos(s * r_j)
__global__ void pos_add_kernel(const float* __restrict__ x, float* __restrict__ out) {
    int idx = blockIdx.x * blockDim.x + threadIdx.x;
    if (idx >= S * D) return;
    int s = idx / D;
    int j = idx % D;
    int jj = (j < D / 2) ? j : j - D / 2;
    float rate = expf(-(float)jj * (logf(10000.0f) / (float)(D / 2)));
    float ang = (float)s * rate;
    float pe = (j < D / 2) ? sinf(ang) : cosf(ang);
    out[idx] = x[idx] + pe;
}

// ---------------- fp32 tiled GEMM: C = A[MxK] @ B[KxN] + bias, opt relu ----
__global__ __launch_bounds__(256)
void sgemm_kernel(const float* __restrict__ A, const float* __restrict__ B,
                  const float* __restrict__ bias, float* __restrict__ C,
                  int M, int N, int K, int relu)
{
    __shared__ float As[BM][BK];      // [m][k]
    __shared__ float Bs[BK][BN];      // [k][n]
    const int tid = threadIdx.x;
    const int bm = blockIdx.y * BM;
    const int bn = blockIdx.x * BN;
    const int tx = tid & 15;          // n quad
    const int ty = tid >> 4;          // m quad
    const int ar = tid >> 2;          // A stage row
    const int ac = (tid & 3) * 4;     // A stage col
    const int br = tid >> 4;          // B stage row
    const int bc = (tid & 15) * 4;    // B stage col

    float acc[4][4] = {};

    for (int k0 = 0; k0 < K; k0 += BK) {
        *(float4*)&As[ar][ac] = *(const float4*)&A[(size_t)(bm + ar) * K + k0 + ac];
        *(float4*)&Bs[br][bc] = *(const float4*)&B[(size_t)(k0 + br) * N + bn + bc];
        __syncthreads();
#pragma unroll
        for (int k = 0; k < BK; ++k) {
            float a0 = As[ty * 4 + 0][k];
            float a1 = As[ty * 4 + 1][k];
            float a2 = As[ty * 4 + 2][k];
            float a3 = As[ty * 4 + 3][k];
            float4 b = *(float4*)&Bs[k][tx * 4];
            acc[0][0] += a0 * b.x; acc[0][1] += a0 * b.y; acc[0][2] += a0 * b.z; acc[0][3] += a0 * b.w;
            acc[1][0] += a1 * b.x; acc[1][1] += a1 * b.y; acc[1][2] += a1 * b.z; acc[1][3] += a1 * b.w;
            acc[2][0] += a2 * b.x; acc[2][1] += a2 * b.y; acc[2][2] += a2 * b.z; acc[2][3] += a2 * b.w;
            acc[3][0] += a3 * b.x; acc[3][1] += a3 * b.y; acc[3][2] += a3 * b.z; acc[3][3] += a3 * b.w;
        }
        __syncthreads();
    }

#pragma unroll
    for (int i = 0; i < 4; ++i) {
        int row = bm + ty * 4 + i;
        float4 bv = *(const float4*)&bias[bn + tx * 4];
        float4 o;
        o.x = acc[i][0] + bv.x;
        o.y = acc[i][1] + bv.y;
        o.z = acc[i][2] + bv.z;
        o.w = acc[i][3] + bv.w;
        if (relu) {
            o.x = fmaxf(o.x, 0.f); o.y = fmaxf(o.y, 0.f);
            o.z = fmaxf(o.z, 0.f); o.w = fmaxf(o.w, 0.f);
        }
        *(float4*)&C[(size_t)row * N + bn + tx * 4] = o;
    }
}

// ---------------- streaming-softmax attention ----------------
// One wave per query row of one head; 64-key chunks staged in LDS.
// Layout: Q/K/V/Out are [S, D] with head h occupying columns [h*64, h*64+64).
template<int CAUSAL>
__global__ __launch_bounds__(256)
void attn_kernel(const float* __restrict__ Q, const float* __restrict__ Km,
                 const float* __restrict__ Vm, float* __restrict__ Out)
{
    __shared__ float Ks[64][65];
    __shared__ float Vs[64][65];
    const int h = blockIdx.y;
    const int tid = threadIdx.x;
    const int wave = tid >> 6;
    const int lane = tid & 63;
    const int qrow = blockIdx.x * 4 + wave;

    float qreg = Q[(size_t)qrow * D + h * DH + lane] * 0.125f;  // 1/sqrt(64)
    float m = -1e30f, lsum = 0.f, acc = 0.f;

    const int nch = CAUSAL ? ((blockIdx.x * 4 + 3) >> 6) + 1 : (S / 64);
    for (int c = 0; c < nch; ++c) {
        // cooperative stage of K,V chunk (64 keys x 64 dims)
#pragma unroll
        for (int i = 0; i < 16; ++i) {
            int idx = tid + i * 256;
            int r = idx >> 6, d = idx & 63;
            Ks[r][d] = Km[(size_t)(c * 64 + r) * D + h * DH + d];
            Vs[r][d] = Vm[(size_t)(c * 64 + r) * D + h * DH + d];
        }
        __syncthreads();

        if (!CAUSAL || c * 64 <= qrow) {
            // lane j computes score for key c*64+j
            float s = 0.f;
#pragma unroll
            for (int d = 0; d < 64; ++d) {
                float qd = __shfl(qreg, d);
                s += qd * Ks[lane][d];
            }
            int kk = c * 64 + lane;
            if (CAUSAL && kk > qrow) s = -1e30f;

            float cm = s;
#pragma unroll
            for (int off = 32; off > 0; off >>= 1) cm = fmaxf(cm, __shfl_xor(cm, off));
            float mnew = fmaxf(m, cm);
            float scale = __expf(m - mnew);
            float p = __expf(s - mnew);
            float ps = p;
#pragma unroll
            for (int off = 32; off > 0; off >>= 1) ps += __shfl_xor(ps, off);
            lsum = lsum * scale + ps;
            acc *= scale;
#pragma unroll
            for (int j = 0; j < 64; ++j) {
                float pj = __shfl(p, j);
                acc += pj * Vs[j][lane];
            }
            m = mnew;
        }
        __syncthreads();
    }
    Out[(size_t)qrow * D + h * DH + lane] = acc / lsum;
}

// ---------------- residual add + layernorm ----------------
__global__ __launch_bounds__(128)
void add_ln_kernel(const float* __restrict__ a, const float* __restrict__ b,
                   const float* __restrict__ g, const float* __restrict__ beta,
                   float* __restrict__ out)
{
    const int row = blockIdx.x;
    const int tid = threadIdx.x;
    float4 av = *(const float4*)&a[(size_t)row * D + tid * 4];
    float4 bv = *(const float4*)&b[(size_t)row * D + tid * 4];
    float4 s;
    s.x = av.x + bv.x; s.y = av.y + bv.y; s.z = av.z + bv.z; s.w = av.w + bv.w;
    float sum = s.x + s.y + s.z + s.w;
    float sq = s.x * s.x + s.y * s.y + s.z * s.z + s.w * s.w;
#pragma unroll
    for (int off = 32; off > 0; off >>= 1) {
        sum += __shfl_xor(sum, off);
        sq  += __shfl_xor(sq, off);
    }
    __shared__ float red[4];
    if ((tid & 63) == 0) { red[(tid >> 6) * 2] = sum; red[(tid >> 6) * 2 + 1] = sq; }
    __syncthreads();
    sum = red[0] + red[2];
    sq  = red[1] + red[3];
    float mu = sum / (float)D;
    float var = sq / (float)D - mu * mu;
    float rs = rsqrtf(var + 1e-6f);
    float4 gv = *(const float4*)&g[tid * 4];
    float4 bt = *(const float4*)&beta[tid * 4];
    float4 o;
    o.x = (s.x - mu) * rs * gv.x + bt.x;
    o.y = (s.y - mu) * rs * gv.y + bt.y;
    o.z = (s.z - mu) * rs * gv.z + bt.z;
    o.w = (s.w - mu) * rs * gv.w + bt.w;
    *(float4*)&out[(size_t)row * D + tid * 4] = o;
}

extern "C" void kernel_launch(void* const* d_in, const int* in_sizes, int n_in,
                              void* d_out, int out_size, void* d_ws, size_t ws_size,
                              hipStream_t stream)
{
    const float* x   = (const float*)d_in[0];
    const float* enc = (const float*)d_in[1];
    const float* a1w = (const float*)d_in[2];
    const float* a1b = (const float*)d_in[3];
    const float* a2w = (const float*)d_in[4];
    const float* a2b = (const float*)d_in[5];
    const float* fw1 = (const float*)d_in[6];
    const float* fb1 = (const float*)d_in[7];
    const float* fw2 = (const float*)d_in[8];
    const float* fb2 = (const float*)d_in[9];
    const float* lng = (const float*)d_in[10];
    const float* lnb = (const float*)d_in[11];
    float* out = (float*)d_out;

    float* ws = (float*)d_ws;
    const size_t SD = (size_t)S * D;
    float* xb   = ws;
    float* q    = ws + SD;
    float* kbuf = ws + 2 * SD;
    float* vbuf = ws + 3 * SD;
    float* att  = ws + 4 * SD;
    float* ao   = ws + 5 * SD;
    float* ffh  = ws + 6 * SD;   // S*F = 4*SD floats

    pos_add_kernel<<<(S * D + 255) / 256, 256, 0, stream>>>(x, xb);

    for (int l = 0; l < NLAYER; ++l) {
        const float* w = a1w + (size_t)l * 4 * D * D;
        const float* b = a1b + (size_t)l * 4 * D;
        sgemm_kernel<<<dim3(D / BN, S / BM), 256, 0, stream>>>(xb, w,             b,         q,    S, D, D, 0);
        sgemm_kernel<<<dim3(D / BN, S / BM), 256, 0, stream>>>(xb, w + D * D,     b + D,     kbuf, S, D, D, 0);
        sgemm_kernel<<<dim3(D / BN, S / BM), 256, 0, stream>>>(xb, w + 2 * D * D, b + 2 * D, vbuf, S, D, D, 0);
        attn_kernel<1><<<dim3(S / 4, H), 256, 0, stream>>>(q, kbuf, vbuf, att);
        sgemm_kernel<<<dim3(D / BN, S / BM), 256, 0, stream>>>(att, w + 3 * D * D, b + 3 * D, ao,  S, D, D, 0);
        add_ln_kernel<<<S, 128, 0, stream>>>(xb, ao, lng + (size_t)(l * 3 + 0) * D, lnb + (size_t)(l * 3 + 0) * D, xb);

        w = a2w + (size_t)l * 4 * D * D;
        b = a2b + (size_t)l * 4 * D;
        sgemm_kernel<<<dim3(D / BN, S / BM), 256, 0, stream>>>(xb,  w,             b,         q,    S, D, D, 0);
        sgemm_kernel<<<dim3(D / BN, S / BM), 256, 0, stream>>>(enc, w + D * D,     b + D,     kbuf, S, D, D, 0);
        sgemm_kernel<<<dim3(D / BN, S / BM), 256, 0, stream>>>(enc, w + 2 * D * D, b + 2 * D, vbuf, S, D, D, 0);
        attn_kernel<0><<<dim3(S / 4, H), 256, 0, stream>>>(q, kbuf, vbuf, att);
        sgemm_kernel<<<dim3(D / BN, S / BM), 256, 0, stream>>>(att, w + 3 * D * D, b + 3 * D, ao,  S, D, D, 0);
        add_ln_kernel<<<S, 128, 0, stream>>>(xb, ao, lng + (size_t)(l * 3 + 1) * D, lnb + (size_t)(l * 3 + 1) * D, xb);

        sgemm_kernel<<<dim3(F / BN, S / BM), 256, 0, stream>>>(xb,  fw1 + (size_t)l * D * F, fb1 + (size_t)l * F, ffh, S, F, D, 1);
        sgemm_kernel<<<dim3(D / BN, S / BM), 256, 0, stream>>>(ffh, fw2 + (size_t)l * F * D, fb2 + (size_t)l * D, ao,  S, D, F, 0);
        float* dst = (l == NLAYER - 1) ? out : xb;
        add_ln_kernel<<<S, 128, 0, stream>>>(xb, ao, lng + (size_t)(l * 3 + 2) * D, lnb + (size_t)(l * 3 + 2) * D, dst);
    }
}

// Round 2
// 656.827 us; speedup vs baseline: 8.0497x; 8.0497x over previous
//
#include <hip/hip_runtime.h>
#include <hip/hip_bf16.h>
#include <math.h>

#define S 2048
#define D 512
#define H 8
#define DH 64
#define F 2048
#define NLAYER 2
#define QKVLD 1536   // qkv buffer row stride (3*D)

typedef __attribute__((ext_vector_type(8))) short bf16x8;
typedef __attribute__((ext_vector_type(4))) float f32x4;
typedef __hip_bfloat16 bf16;

typedef __attribute__((address_space(3))) unsigned int lds_u32;
typedef __attribute__((address_space(1))) const unsigned int glb_u32;

__device__ __forceinline__ void gld16(const void* g, void* l) {
    __builtin_amdgcn_global_load_lds((glb_u32*)g, (lds_u32*)l, 16, 0, 0);
}

// ---------------- positional encoding add (fp32 + bf16 mirror) ----------------
__global__ void pos_add_kernel(const float* __restrict__ x, float* __restrict__ outF,
                               bf16* __restrict__ outB) {
    int idx = blockIdx.x * blockDim.x + threadIdx.x;
    if (idx >= S * D) return;
    int s = idx / D;
    int j = idx % D;
    int jj = (j < D / 2) ? j : j - D / 2;
    float rate = expf(-(float)jj * (logf(10000.0f) / (float)(D / 2)));
    float ang = (float)s * rate;
    float pe = (j < D / 2) ? sinf(ang) : cosf(ang);
    float v = x[idx] + pe;
    outF[idx] = v;
    outB[idx] = __float2bfloat16(v);
}

// ---------------- fp32 -> bf16 convert ----------------
__global__ void cvt_kernel(const float* __restrict__ in, bf16* __restrict__ out, int n) {
    int idx = blockIdx.x * blockDim.x + threadIdx.x;
    if (idx < n) out[idx] = __float2bfloat16(in[idx]);
}

// ---------------- transpose + convert: out[C][R] bf16 = in[R][C]^T ----------------
__global__ __launch_bounds__(256)
void transpose_cvt(const float* __restrict__ in, bf16* __restrict__ out, int R, int C) {
    __shared__ float t[64][65];
    const int rb = blockIdx.y * 64, cb = blockIdx.x * 64;
    for (int i = threadIdx.x; i < 4096; i += 256) {
        int r = i >> 6, c = i & 63;
        t[r][c] = in[(size_t)(rb + r) * C + cb + c];
    }
    __syncthreads();
    for (int i = threadIdx.x; i < 4096; i += 256) {
        int r = i >> 6, c = i & 63;
        out[(size_t)(cb + r) * R + rb + c] = __float2bfloat16(t[c][r]);
    }
}

// ---------------- bf16 MFMA GEMM: out = A[M,K] @ Bt[N,K]^T + bias ----------------
// 128x128 tile, BK=32, 4 waves (2x2), global_load_lds staging with
// (row>>1)&3 XOR slot swizzle (linear LDS dest + pre-swizzled global source).
__global__ __launch_bounds__(256)
void gemm_bf16(const bf16* __restrict__ A, const bf16* __restrict__ Bt,
               const float* __restrict__ bias, float* __restrict__ outF,
               bf16* __restrict__ outB, int K, int ldc, int relu)
{
    __shared__ char lds[16384];   // As [128][32] bf16 @0, Bs [128][32] bf16 @8192
    const int tid = threadIdx.x;
    const int w = tid >> 6, l = tid & 63;
    const int l15 = l & 15, l4 = l >> 4;
    const int bm = blockIdx.y * 128, bn = blockIdx.x * 128;
    const int wr = (w >> 1) * 64, wc = (w & 1) * 64;

    f32x4 acc[4][4] = {};
    const int sp = l & 3;          // physical 16B slot within 64B row

    for (int k0 = 0; k0 < K; k0 += 32) {
#pragma unroll
        for (int i = 0; i < 2; ++i) {
            int row = w * 32 + i * 16 + (l >> 2);
            int sl = (sp ^ ((row >> 1) & 3)) * 8;   // logical k-offset (elems)
            gld16(A  + (size_t)(bm + row) * K + k0 + sl, lds + w * 2048 + i * 1024);
            gld16(Bt + (size_t)(bn + row) * K + k0 + sl, lds + 8192 + w * 2048 + i * 1024);
        }
        __syncthreads();
        bf16x8 af[4], bfr[4];
#pragma unroll
        for (int i = 0; i < 4; ++i) {
            int row = wr + i * 16 + l15;
            af[i] = *(const bf16x8*)(lds + row * 64 + ((l4 ^ ((row >> 1) & 3)) << 4));
        }
#pragma unroll
        for (int j = 0; j < 4; ++j) {
            int row = wc + j * 16 + l15;
            bfr[j] = *(const bf16x8*)(lds + 8192 + row * 64 + ((l4 ^ ((row >> 1) & 3)) << 4));
        }
#pragma unroll
        for (int i = 0; i < 4; ++i)
#pragma unroll
            for (int j = 0; j < 4; ++j)
                acc[i][j] = __builtin_amdgcn_mfma_f32_16x16x32_bf16(af[i], bfr[j], acc[i][j], 0, 0, 0);
        __syncthreads();
    }

#pragma unroll
    for (int i = 0; i < 4; ++i)
#pragma unroll
        for (int j = 0; j < 4; ++j)
#pragma unroll
            for (int q = 0; q < 4; ++q) {
                int row = bm + wr + i * 16 + l4 * 4 + q;
                int col = bn + wc + j * 16 + l15;
                float v = acc[i][j][q] + bias[col];
                if (relu) v = fmaxf(v, 0.f);
                if (outF) outF[(size_t)row * ldc + col] = v;
                if (outB) outB[(size_t)row * ldc + col] = __float2bfloat16(v);
            }
}

// ---------------- MFMA flash attention ----------------
// Block = 4 waves, 64 q-rows (16/wave), one (qtile, head). 64-key chunks.
// QKV layout: [S][1536] bf16, Q at col h*64, K at 512+h*64, V at 1024+h*64.
template<int CAUSAL>
__global__ __launch_bounds__(256)
void attn_mfma(const bf16* __restrict__ QKV, bf16* __restrict__ O)
{
    __shared__ char lds[24576];  // Ks [64][64] @0 (swz), Vt [64][64] @8192 (swz), Ps 4x[16][64] @16384 (swz)
    const int tid = threadIdx.x;
    const int w = tid >> 6, l = tid & 63;
    const int l15 = l & 15, l4 = l >> 4;
    const int h = blockIdx.y, qt = blockIdx.x;
    const int qbase = qt * 64 + w * 16;

    bf16x8 aq[2];
#pragma unroll
    for (int s = 0; s < 2; ++s)
        aq[s] = *(const bf16x8*)(QKV + (size_t)(qbase + l15) * QKVLD + h * DH + s * 32 + l4 * 8);

    f32x4 o[4] = {};
    float mrun[4], lrun[4];
#pragma unroll
    for (int j = 0; j < 4; ++j) { mrun[j] = -1e30f; lrun[j] = 0.f; }

    const int nch = CAUSAL ? (qt + 1) : (S / 64);
    for (int c = 0; c < nch; ++c) {
        const int kbase = c * 64;
        // stage K: rows=keys, 128B rows, XOR slot swizzle (row&7)
#pragma unroll
        for (int i = 0; i < 2; ++i) {
            int cc = w * 2 + i;
            int row = cc * 8 + (l >> 3);
            int koff = ((l & 7) ^ (row & 7)) * 8;
            gld16(QKV + (size_t)(kbase + row) * QKVLD + D + h * DH + koff, lds + cc * 1024);
        }
        // stage V transposed: Vt[d][key], lane = key (conflict-free writes)
        {
            const bf16* vp = QKV + (size_t)(kbase + l) * QKVLD + 2 * D + h * DH + w * 16;
            bf16x8 v0 = *(const bf16x8*)vp;
            bf16x8 v1 = *(const bf16x8*)(vp + 8);
#pragma unroll
            for (int u = 0; u < 2; ++u)
#pragma unroll
                for (int jj = 0; jj < 8; ++jj) {
                    int d = w * 16 + u * 8 + jj;
                    int byte = (8192 + d * 128 + l * 2) ^ ((d & 7) << 4);
                    *(short*)(lds + byte) = u ? v1[jj] : v0[jj];
                }
        }
        __syncthreads();

        // QK^T: st[t] covers keys t*16..t*16+15; C rows=q, cols=key
        f32x4 st[4];
#pragma unroll
        for (int t = 0; t < 4; ++t) {
            f32x4 sacc = {0.f, 0.f, 0.f, 0.f};
#pragma unroll
            for (int s = 0; s < 2; ++s) {
                int row = t * 16 + l15;
                int slot = (s * 4 + l4) ^ (row & 7);
                bf16x8 kf = *(const bf16x8*)(lds + row * 128 + slot * 16);
                sacc = __builtin_amdgcn_mfma_f32_16x16x32_bf16(aq[s], kf, sacc, 0, 0, 0);
            }
            st[t] = sacc;
        }

        // online softmax per accumulator row j (q row = qbase + l4*4 + j)
#pragma unroll
        for (int j = 0; j < 4; ++j) {
            float sv[4];
#pragma unroll
            for (int t = 0; t < 4; ++t) {
                float v = st[t][j] * 0.125f;
                if (CAUSAL && c == qt) {
                    int key = kbase + t * 16 + l15;
                    int qr = qbase + l4 * 4 + j;
                    if (key > qr) v = -1e30f;
                }
                sv[t] = v;
            }
            float mx = fmaxf(fmaxf(sv[0], sv[1]), fmaxf(sv[2], sv[3]));
            mx = fmaxf(mx, __shfl_xor(mx, 1));
            mx = fmaxf(mx, __shfl_xor(mx, 2));
            mx = fmaxf(mx, __shfl_xor(mx, 4));
            mx = fmaxf(mx, __shfl_xor(mx, 8));
            float mnew = fmaxf(mrun[j], mx);
            float scl = __expf(mrun[j] - mnew);
            mrun[j] = mnew;
            float ps = 0.f;
            const int qrl = l4 * 4 + j;
#pragma unroll
            for (int t = 0; t < 4; ++t) {
                float p = __expf(sv[t] - mnew);
                ps += p;
                int byte = (16384 + w * 2048 + qrl * 128 + (t * 16 + l15) * 2) ^ ((qrl & 7) << 4);
                *(short*)(lds + byte) = __builtin_bit_cast(short, __float2bfloat16(p));
            }
            ps += __shfl_xor(ps, 1);
            ps += __shfl_xor(ps, 2);
            ps += __shfl_xor(ps, 4);
            ps += __shfl_xor(ps, 8);
            lrun[j] = lrun[j] * scl + ps;
#pragma unroll
            for (int dt = 0; dt < 4; ++dt) o[dt][j] *= scl;
        }

        // PV: o[dt] += P @ V  (A-frag from Ps, B-frag from Vt, both swizzled)
#pragma unroll
        for (int dt = 0; dt < 4; ++dt) {
#pragma unroll
            for (int s = 0; s < 2; ++s) {
                int pslot = (s * 4 + l4) ^ (l15 & 7);
                bf16x8 pf = *(const bf16x8*)(lds + 16384 + w * 2048 + l15 * 128 + pslot * 16);
                int d = dt * 16 + l15;
                int vslot = (s * 4 + l4) ^ (d & 7);
                bf16x8 vf = *(const bf16x8*)(lds + 8192 + d * 128 + vslot * 16);
                o[dt] = __builtin_amdgcn_mfma_f32_16x16x32_bf16(pf, vf, o[dt], 0, 0, 0);
            }
        }
        __syncthreads();
    }

#pragma unroll
    for (int dt = 0; dt < 4; ++dt)
#pragma unroll
        for (int j = 0; j < 4; ++j) {
            int row = qbase + l4 * 4 + j;
            O[(size_t)row * D + h * DH + dt * 16 + l15] = __float2bfloat16(o[dt][j] / lrun[j]);
        }
}

// ---------------- residual add + layernorm (fp32, optional bf16 mirror) ----------------
__global__ __launch_bounds__(128)
void add_ln_kernel(const float* __restrict__ a, const float* __restrict__ b,
                   const float* __restrict__ g, const float* __restrict__ beta,
                   float* __restrict__ outF, bf16* __restrict__ outB)
{
    const int row = blockIdx.x;
    const int tid = threadIdx.x;
    float4 av = *(const float4*)&a[(size_t)row * D + tid * 4];
    float4 bv = *(const float4*)&b[(size_t)row * D + tid * 4];
    float4 s;
    s.x = av.x + bv.x; s.y = av.y + bv.y; s.z = av.z + bv.z; s.w = av.w + bv.w;
    float sum = s.x + s.y + s.z + s.w;
    float sq = s.x * s.x + s.y * s.y + s.z * s.z + s.w * s.w;
#pragma unroll
    for (int off = 32; off > 0; off >>= 1) {
        sum += __shfl_xor(sum, off);
        sq  += __shfl_xor(sq, off);
    }
    __shared__ float red[4];
    if ((tid & 63) == 0) { red[(tid >> 6) * 2] = sum; red[(tid >> 6) * 2 + 1] = sq; }
    __syncthreads();
    sum = red[0] + red[2];
    sq  = red[1] + red[3];
    float mu = sum / (float)D;
    float var = sq / (float)D - mu * mu;
    float rs = rsqrtf(var + 1e-6f);
    float4 gv = *(const float4*)&g[tid * 4];
    float4 bt = *(const float4*)&beta[tid * 4];
    float4 o;
    o.x = (s.x - mu) * rs * gv.x + bt.x;
    o.y = (s.y - mu) * rs * gv.y + bt.y;
    o.z = (s.z - mu) * rs * gv.z + bt.z;
    o.w = (s.w - mu) * rs * gv.w + bt.w;
    *(float4*)&outF[(size_t)row * D + tid * 4] = o;
    if (outB) {
        outB[(size_t)row * D + tid * 4 + 0] = __float2bfloat16(o.x);
        outB[(size_t)row * D + tid * 4 + 1] = __float2bfloat16(o.y);
        outB[(size_t)row * D + tid * 4 + 2] = __float2bfloat16(o.z);
        outB[(size_t)row * D + tid * 4 + 3] = __float2bfloat16(o.w);
    }
}

extern "C" void kernel_launch(void* const* d_in, const int* in_sizes, int n_in,
                              void* d_out, int out_size, void* d_ws, size_t ws_size,
                              hipStream_t stream)
{
    const float* x   = (const float*)d_in[0];
    const float* enc = (const float*)d_in[1];
    const float* a1w = (const float*)d_in[2];
    const float* a1b = (const float*)d_in[3];
    const float* a2w = (const float*)d_in[4];
    const float* a2b = (const float*)d_in[5];
    const float* fw1 = (const float*)d_in[6];
    const float* fb1 = (const float*)d_in[7];
    const float* fw2 = (const float*)d_in[8];
    const float* fb2 = (const float*)d_in[9];
    const float* lng = (const float*)d_in[10];
    const float* lnb = (const float*)d_in[11];
    float* out = (float*)d_out;

    char* wsb = (char*)d_ws;
    float* xb   = (float*)(wsb);                       // 4 MB
    float* ao   = (float*)(wsb + ((size_t)4 << 20));   // 4 MB
    bf16* xb16  = (bf16*)(wsb + ((size_t)8 << 20));    // 2 MB
    bf16* enc16 = (bf16*)(wsb + ((size_t)10 << 20));   // 2 MB
    bf16* att16 = (bf16*)(wsb + ((size_t)12 << 20));   // 2 MB
    bf16* qkv16 = (bf16*)(wsb + ((size_t)14 << 20));   // 8 MB (shared with ffh16)
    bf16* ffh16 = qkv16;
    bf16* wts   = (bf16*)(wsb + ((size_t)22 << 20));   // 16 MB
    const size_t WCH = 1048576;   // bf16 elems per (group, layer) weight chunk
    const size_t DD = (size_t)D * D, DF = (size_t)D * F;

    // ---- weight prep: transpose + bf16 convert ----
    for (int l = 0; l < NLAYER; ++l) {
        for (int g = 0; g < 4; ++g) {
            transpose_cvt<<<dim3(8, 8), 256, 0, stream>>>(
                a1w + (size_t)(l * 4 + g) * DD, wts + (size_t)(0 + l) * WCH + g * DD, D, D);
            transpose_cvt<<<dim3(8, 8), 256, 0, stream>>>(
                a2w + (size_t)(l * 4 + g) * DD, wts + (size_t)(2 + l) * WCH + g * DD, D, D);
        }
        transpose_cvt<<<dim3(32, 8), 256, 0, stream>>>(fw1 + (size_t)l * DF, wts + (size_t)(4 + l) * WCH, D, F);
        transpose_cvt<<<dim3(8, 32), 256, 0, stream>>>(fw2 + (size_t)l * DF, wts + (size_t)(6 + l) * WCH, F, D);
    }
    cvt_kernel<<<(S * D + 255) / 256, 256, 0, stream>>>(enc, enc16, S * D);
    pos_add_kernel<<<(S * D + 255) / 256, 256, 0, stream>>>(x, xb, xb16);

    for (int l = 0; l < NLAYER; ++l) {
        const bf16* A1T = wts + (size_t)(0 + l) * WCH;   // [4D][D]: rows 0..1535 qkv^T, 1536.. wo^T
        const bf16* A2T = wts + (size_t)(2 + l) * WCH;
        const bf16* W1T = wts + (size_t)(4 + l) * WCH;   // [2048][512]
        const bf16* W2T = wts + (size_t)(6 + l) * WCH;   // [512][2048]
        const float* b1v = a1b + (size_t)l * 4 * D;
        const float* b2v = a2b + (size_t)l * 4 * D;

        // self-attention
        gemm_bf16<<<dim3(12, 16), 256, 0, stream>>>(xb16, A1T, b1v, nullptr, qkv16, D, QKVLD, 0);
        attn_mfma<1><<<dim3(32, 8), 256, 0, stream>>>(qkv16, att16);
        gemm_bf16<<<dim3(4, 16), 256, 0, stream>>>(att16, A1T + 3 * DD, b1v + 3 * D, ao, nullptr, D, D, 0);
        add_ln_kernel<<<S, 128, 0, stream>>>(xb, ao, lng + (size_t)(l * 3 + 0) * D, lnb + (size_t)(l * 3 + 0) * D, xb, xb16);

        // cross-attention
        gemm_bf16<<<dim3(4, 16), 256, 0, stream>>>(xb16, A2T, b2v, nullptr, qkv16, D, QKVLD, 0);
        gemm_bf16<<<dim3(8, 16), 256, 0, stream>>>(enc16, A2T + DD, b2v + D, nullptr, qkv16 + D, D, QKVLD, 0);
        attn_mfma<0><<<dim3(32, 8), 256, 0, stream>>>(qkv16, att16);
        gemm_bf16<<<dim3(4, 16), 256, 0, stream>>>(att16, A2T + 3 * DD, b2v + 3 * D, ao, nullptr, D, D, 0);
        add_ln_kernel<<<S, 128, 0, stream>>>(xb, ao, lng + (size_t)(l * 3 + 1) * D, lnb + (size_t)(l * 3 + 1) * D, xb, xb16);

        // FFN
        gemm_bf16<<<dim3(16, 16), 256, 0, stream>>>(xb16, W1T, fb1 + (size_t)l * F, nullptr, ffh16, D, F, 1);
        gemm_bf16<<<dim3(4, 16), 256, 0, stream>>>(ffh16, W2T, fb2 + (size_t)l * D, ao, nullptr, F, D, 0);
        float* dstF = (l == NLAYER - 1) ? out : xb;
        bf16* dstB = (l == NLAYER - 1) ? nullptr : xb16;
        add_ln_kernel<<<S, 128, 0, stream>>>(xb, ao, lng + (size_t)(l * 3 + 2) * D, lnb + (size_t)(l * 3 + 2) * D, dstF, dstB);
    }
}

// Round 3
// 645.940 us; speedup vs baseline: 8.1854x; 1.0169x over previous
//
#include <hip/hip_runtime.h>
#include <hip/hip_bf16.h>
#include <math.h>

#define S 2048
#define D 512
#define H 8
#define DH 64
#define F 2048
#define NLAYER 2
#define QKVLD 1536   // qkv buffer row stride (3*D)

typedef __attribute__((ext_vector_type(8))) short bf16x8;
typedef __attribute__((ext_vector_type(4))) float f32x4;
typedef __hip_bfloat16 bf16;

typedef __attribute__((address_space(3))) unsigned int lds_u32;
typedef __attribute__((address_space(1))) const unsigned int glb_u32;

__device__ __forceinline__ void gld16(const void* g, void* l) {
    __builtin_amdgcn_global_load_lds((glb_u32*)g, (lds_u32*)l, 16, 0, 0);
}

// ---------------- positional encoding add (fp32 + bf16 mirror) ----------------
__global__ void pos_add_kernel(const float* __restrict__ x, float* __restrict__ outF,
                               bf16* __restrict__ outB) {
    int idx = blockIdx.x * blockDim.x + threadIdx.x;
    if (idx >= S * D) return;
    int s = idx / D;
    int j = idx % D;
    int jj = (j < D / 2) ? j : j - D / 2;
    float rate = expf(-(float)jj * (logf(10000.0f) / (float)(D / 2)));
    float ang = (float)s * rate;
    float pe = (j < D / 2) ? sinf(ang) : cosf(ang);
    float v = x[idx] + pe;
    outF[idx] = v;
    outB[idx] = __float2bfloat16(v);
}

// ---------------- fp32 -> bf16 convert ----------------
__global__ void cvt_kernel(const float* __restrict__ in, bf16* __restrict__ out, int n) {
    int idx = blockIdx.x * blockDim.x + threadIdx.x;
    if (idx < n) out[idx] = __float2bfloat16(in[idx]);
}

// ---------------- batched transpose + convert ----------------
// z-th matrix: src = in + z*inStride [R][C]; dst = out + (z/mpl)*outL + (z%mpl)*outM, [C][R]
__global__ __launch_bounds__(256)
void transpose_cvt_b(const float* __restrict__ in, bf16* __restrict__ out, int R, int C,
                     size_t inStride, size_t outL, size_t outM, int mpl)
{
    __shared__ float t[64][65];
    const int z = blockIdx.z;
    const float* src = in + (size_t)z * inStride;
    bf16* dst = out + (size_t)(z / mpl) * outL + (size_t)(z % mpl) * outM;
    const int rb = blockIdx.x * 64, cb = blockIdx.y * 64;
    for (int i = threadIdx.x; i < 4096; i += 256) {
        int r = i >> 6, c = i & 63;
        t[r][c] = src[(size_t)(rb + r) * C + cb + c];
    }
    __syncthreads();
    for (int i = threadIdx.x; i < 4096; i += 256) {
        int r = i >> 6, c = i & 63;
        dst[(size_t)(cb + r) * R + rb + c] = __float2bfloat16(t[c][r]);
    }
}

// ---------------- V transpose: Vt[d][s] = QKV[s][1024 + d] ----------------
__global__ __launch_bounds__(256)
void vt_kernel(const bf16* __restrict__ qkv, bf16* __restrict__ vt)
{
    __shared__ short t[64][72];
    const int sb = blockIdx.x * 64;   // seq tile
    const int db = blockIdx.y * 64;   // d tile (0..511 across heads)
    for (int i = threadIdx.x; i < 512; i += 256) {
        int r = i >> 3, c8 = (i & 7) * 8;
        *(bf16x8*)&t[r][c8] = *(const bf16x8*)(qkv + (size_t)(sb + r) * QKVLD + 2 * D + db + c8);
    }
    __syncthreads();
    for (int i = threadIdx.x; i < 512; i += 256) {
        int d = i >> 3, s8 = (i & 7) * 8;
        bf16x8 v;
#pragma unroll
        for (int j = 0; j < 8; ++j) v[j] = t[s8 + j][d];
        *(bf16x8*)(vt + (size_t)(db + d) * S + sb + s8) = v;
    }
}

// ---------------- bf16 MFMA GEMM: out = A[M,K] @ Bt[N,K]^T + bias ----------------
template<int BM, int BN>
__global__ __launch_bounds__(256)
void gemm_bf16(const bf16* __restrict__ A, const bf16* __restrict__ Bt,
               const float* __restrict__ bias, float* __restrict__ outF,
               bf16* __restrict__ outB, int K, int ldc, int relu)
{
    constexpr int MI = BM / 32, NJ = BN / 32;
    __shared__ char lds[(BM + BN) * 64];
    const int tid = threadIdx.x;
    const int w = tid >> 6, l = tid & 63;
    const int l15 = l & 15, l4 = l >> 4;
    const int bm = blockIdx.y * BM, bn = blockIdx.x * BN;
    const int wr = (w >> 1) * (BM / 2), wc = (w & 1) * (BN / 2);

    f32x4 acc[MI][NJ] = {};
    const int sp = l & 3;          // physical 16B slot within 64B row

    for (int k0 = 0; k0 < K; k0 += 32) {
#pragma unroll
        for (int i = 0; i < BM / 64; ++i) {
            int row = w * (BM / 4) + i * 16 + (l >> 2);
            int sl = (sp ^ ((row >> 1) & 3)) * 8;
            gld16(A + (size_t)(bm + row) * K + k0 + sl, lds + (w * (BM / 4) + i * 16) * 64);
        }
#pragma unroll
        for (int i = 0; i < BN / 64; ++i) {
            int row = w * (BN / 4) + i * 16 + (l >> 2);
            int sl = (sp ^ ((row >> 1) & 3)) * 8;
            gld16(Bt + (size_t)(bn + row) * K + k0 + sl, lds + BM * 64 + (w * (BN / 4) + i * 16) * 64);
        }
        __syncthreads();
        bf16x8 af[MI], bfr[NJ];
#pragma unroll
        for (int i = 0; i < MI; ++i) {
            int row = wr + i * 16 + l15;
            af[i] = *(const bf16x8*)(lds + row * 64 + ((l4 ^ ((row >> 1) & 3)) << 4));
        }
#pragma unroll
        for (int j = 0; j < NJ; ++j) {
            int row = wc + j * 16 + l15;
            bfr[j] = *(const bf16x8*)(lds + BM * 64 + row * 64 + ((l4 ^ ((row >> 1) & 3)) << 4));
        }
#pragma unroll
        for (int i = 0; i < MI; ++i)
#pragma unroll
            for (int j = 0; j < NJ; ++j)
                acc[i][j] = __builtin_amdgcn_mfma_f32_16x16x32_bf16(af[i], bfr[j], acc[i][j], 0, 0, 0);
        __syncthreads();
    }

#pragma unroll
    for (int i = 0; i < MI; ++i)
#pragma unroll
        for (int j = 0; j < NJ; ++j)
#pragma unroll
            for (int q = 0; q < 4; ++q) {
                int row = bm + wr + i * 16 + l4 * 4 + q;
                int col = bn + wc + j * 16 + l15;
                float v = acc[i][j][q] + bias[col];
                if (relu) v = fmaxf(v, 0.f);
                if (outF) outF[(size_t)row * ldc + col] = v;
                if (outB) outB[(size_t)row * ldc + col] = __float2bfloat16(v);
            }
}

// ---------------- barrier-free MFMA flash attention ----------------
// One wave per block, 16 q-rows. Swapped QK^T (mfma(K,Q)) => lane l holds P
// values for q = l&15, keys (t*16 + (l>>4)*4 + r). K read direct from global
// ([S][QKVLD] rows); V read from pre-transposed Vt[d][s]. P via per-wave LDS.
template<int CAUSAL>
__global__ __launch_bounds__(64)
void attn_mfma2(const bf16* __restrict__ QKV, const bf16* __restrict__ Vt,
                bf16* __restrict__ O)
{
    __shared__ char plds[2048];   // P [16 q][64 keys] bf16, XOR-swizzled
    const int l = threadIdx.x;
    const int l15 = l & 15, l4 = l >> 4;
    const int h = blockIdx.y, qt = blockIdx.x;
    const int qbase = qt * 16;
    const int qr = qbase + l15;   // this lane's q row in swapped layout

    bf16x8 aq[2];
#pragma unroll
    for (int s = 0; s < 2; ++s)
        aq[s] = *(const bf16x8*)(QKV + (size_t)(qbase + l15) * QKVLD + h * DH + s * 32 + l4 * 8);

    f32x4 o[4] = {};              // o[dt]: q = l4*4+reg, d = dt*16+l15
    float mrun = -1e30f, lrun = 0.f;

    const int nch = CAUSAL ? (qt / 4 + 1) : (S / 64);
    for (int c = 0; c < nch; ++c) {
        const int kbase = c * 64;

        // S^T tiles: rows=keys, cols=q
        f32x4 st[4];
#pragma unroll
        for (int t = 0; t < 4; ++t) {
            f32x4 sacc = {0.f, 0.f, 0.f, 0.f};
#pragma unroll
            for (int s = 0; s < 2; ++s) {
                bf16x8 kf = *(const bf16x8*)(QKV + (size_t)(kbase + t * 16 + l15) * QKVLD
                                             + D + h * DH + s * 32 + l4 * 8);
                sacc = __builtin_amdgcn_mfma_f32_16x16x32_bf16(kf, aq[s], sacc, 0, 0, 0);
            }
            st[t] = sacc;
        }

        // per-lane softmax over the 16 held values (all for q = l15)
        float p[4][4];
        float mx = -1e30f;
#pragma unroll
        for (int t = 0; t < 4; ++t)
#pragma unroll
            for (int r = 0; r < 4; ++r) {
                float v = st[t][r] * 0.125f;
                if (CAUSAL && c == nch - 1) {
                    int key = kbase + t * 16 + l4 * 4 + r;
                    if (key > qr) v = -1e30f;
                }
                p[t][r] = v;
                mx = fmaxf(mx, v);
            }
        mx = fmaxf(mx, __shfl_xor(mx, 16));
        mx = fmaxf(mx, __shfl_xor(mx, 32));
        float mnew = fmaxf(mrun, mx);
        float scl = __expf(mrun - mnew);
        mrun = mnew;

        float ps = 0.f;
#pragma unroll
        for (int t = 0; t < 4; ++t) {
            float e0 = __expf(p[t][0] - mnew);
            float e1 = __expf(p[t][1] - mnew);
            float e2 = __expf(p[t][2] - mnew);
            float e3 = __expf(p[t][3] - mnew);
            ps += (e0 + e1) + (e2 + e3);
            unsigned int lo = (unsigned int)(unsigned short)__builtin_bit_cast(short, __float2bfloat16(e0))
                            | ((unsigned int)(unsigned short)__builtin_bit_cast(short, __float2bfloat16(e1)) << 16);
            unsigned int hi = (unsigned int)(unsigned short)__builtin_bit_cast(short, __float2bfloat16(e2))
                            | ((unsigned int)(unsigned short)__builtin_bit_cast(short, __float2bfloat16(e3)) << 16);
            uint2 pk; pk.x = lo; pk.y = hi;
            int byte = (l15 * 128 + t * 32 + l4 * 8) ^ ((l15 & 7) << 4);
            *(uint2*)(plds + byte) = pk;
        }
        ps += __shfl_xor(ps, 16);
        ps += __shfl_xor(ps, 32);
        lrun = lrun * scl + ps;

        // rescale o: row q' = l4*4+j needs scl from lane (l&48)|q'
#pragma unroll
        for (int j = 0; j < 4; ++j) {
            float sj = __shfl(scl, (l & 48) | (l4 * 4 + j));
#pragma unroll
            for (int dt = 0; dt < 4; ++dt) o[dt][j] *= sj;
        }

        // PV: A-frag from plds (row=q=l15, k=key), B-frag from Vt (contiguous)
#pragma unroll
        for (int dt = 0; dt < 4; ++dt) {
#pragma unroll
            for (int s = 0; s < 2; ++s) {
                int byte = (l15 * 128 + s * 64 + l4 * 16) ^ ((l15 & 7) << 4);
                bf16x8 pf = *(const bf16x8*)(plds + byte);
                bf16x8 vf = *(const bf16x8*)(Vt + (size_t)(h * DH + dt * 16 + l15) * S
                                             + kbase + s * 32 + l4 * 8);
                o[dt] = __builtin_amdgcn_mfma_f32_16x16x32_bf16(pf, vf, o[dt], 0, 0, 0);
            }
        }
    }

    float linv[4];
#pragma unroll
    for (int j = 0; j < 4; ++j)
        linv[j] = 1.f / __shfl(lrun, (l & 48) | (l4 * 4 + j));
#pragma unroll
    for (int dt = 0; dt < 4; ++dt)
#pragma unroll
        for (int j = 0; j < 4; ++j) {
            int row = qbase + l4 * 4 + j;
            O[(size_t)row * D + h * DH + dt * 16 + l15] = __float2bfloat16(o[dt][j] * linv[j]);
        }
}

// ---------------- residual add + layernorm (fp32, optional bf16 mirror) ----------------
__global__ __launch_bounds__(128)
void add_ln_kernel(const float* __restrict__ a, const float* __restrict__ b,
                   const float* __restrict__ g, const float* __restrict__ beta,
                   float* __restrict__ outF, bf16* __restrict__ outB)
{
    const int row = blockIdx.x;
    const int tid = threadIdx.x;
    float4 av = *(const float4*)&a[(size_t)row * D + tid * 4];
    float4 bv = *(const float4*)&b[(size_t)row * D + tid * 4];
    float4 s;
    s.x = av.x + bv.x; s.y = av.y + bv.y; s.z = av.z + bv.z; s.w = av.w + bv.w;
    float sum = s.x + s.y + s.z + s.w;
    float sq = s.x * s.x + s.y * s.y + s.z * s.z + s.w * s.w;
#pragma unroll
    for (int off = 32; off > 0; off >>= 1) {
        sum += __shfl_xor(sum, off);
        sq  += __shfl_xor(sq, off);
    }
    __shared__ float red[4];
    if ((tid & 63) == 0) { red[(tid >> 6) * 2] = sum; red[(tid >> 6) * 2 + 1] = sq; }
    __syncthreads();
    sum = red[0] + red[2];
    sq  = red[1] + red[3];
    float mu = sum / (float)D;
    float var = sq / (float)D - mu * mu;
    float rs = rsqrtf(var + 1e-6f);
    float4 gv = *(const float4*)&g[tid * 4];
    float4 bt = *(const float4*)&beta[tid * 4];
    float4 o;
    o.x = (s.x - mu) * rs * gv.x + bt.x;
    o.y = (s.y - mu) * rs * gv.y + bt.y;
    o.z = (s.z - mu) * rs * gv.z + bt.z;
    o.w = (s.w - mu) * rs * gv.w + bt.w;
    *(float4*)&outF[(size_t)row * D + tid * 4] = o;
    if (outB) {
        outB[(size_t)row * D + tid * 4 + 0] = __float2bfloat16(o.x);
        outB[(size_t)row * D + tid * 4 + 1] = __float2bfloat16(o.y);
        outB[(size_t)row * D + tid * 4 + 2] = __float2bfloat16(o.z);
        outB[(size_t)row * D + tid * 4 + 3] = __float2bfloat16(o.w);
    }
}

extern "C" void kernel_launch(void* const* d_in, const int* in_sizes, int n_in,
                              void* d_out, int out_size, void* d_ws, size_t ws_size,
                              hipStream_t stream)
{
    const float* x   = (const float*)d_in[0];
    const float* enc = (const float*)d_in[1];
    const float* a1w = (const float*)d_in[2];
    const float* a1b = (const float*)d_in[3];
    const float* a2w = (const float*)d_in[4];
    const float* a2b = (const float*)d_in[5];
    const float* fw1 = (const float*)d_in[6];
    const float* fb1 = (const float*)d_in[7];
    const float* fw2 = (const float*)d_in[8];
    const float* fb2 = (const float*)d_in[9];
    const float* lng = (const float*)d_in[10];
    const float* lnb = (const float*)d_in[11];
    float* out = (float*)d_out;

    char* wsb = (char*)d_ws;
    float* xb   = (float*)(wsb);                       // 4 MB
    float* ao   = (float*)(wsb + ((size_t)4 << 20));   // 4 MB
    bf16* xb16  = (bf16*)(wsb + ((size_t)8 << 20));    // 2 MB
    bf16* enc16 = (bf16*)(wsb + ((size_t)10 << 20));   // 2 MB
    bf16* att16 = (bf16*)(wsb + ((size_t)12 << 20));   // 2 MB
    bf16* qkv16 = (bf16*)(wsb + ((size_t)14 << 20));   // 6 MB [S][1536]
    bf16* vt16  = (bf16*)(wsb + ((size_t)20 << 20));   // 2 MB [512][S]
    bf16* ffh16 = qkv16;                               // 8 MB (overlaps vt16; disjoint lifetime)
    bf16* wts   = (bf16*)(wsb + ((size_t)22 << 20));   // 16 MB
    const size_t WCH = 1048576;
    const size_t DD = (size_t)D * D, DF = (size_t)D * F;

    // ---- weight prep (batched): transpose + bf16 ----
    transpose_cvt_b<<<dim3(8, 8, 8), 256, 0, stream>>>(a1w, wts,            D, D, DD, WCH, DD, 4);
    transpose_cvt_b<<<dim3(8, 8, 8), 256, 0, stream>>>(a2w, wts + 2 * WCH,  D, D, DD, WCH, DD, 4);
    transpose_cvt_b<<<dim3(8, 32, 2), 256, 0, stream>>>(fw1, wts + 4 * WCH, D, F, DF, WCH, 0, 1);
    transpose_cvt_b<<<dim3(32, 8, 2), 256, 0, stream>>>(fw2, wts + 6 * WCH, F, D, DF, WCH, 0, 1);
    cvt_kernel<<<(S * D + 255) / 256, 256, 0, stream>>>(enc, enc16, S * D);
    pos_add_kernel<<<(S * D + 255) / 256, 256, 0, stream>>>(x, xb, xb16);

    for (int l = 0; l < NLAYER; ++l) {
        const bf16* A1T = wts + (size_t)(0 + l) * WCH;
        const bf16* A2T = wts + (size_t)(2 + l) * WCH;
        const bf16* W1T = wts + (size_t)(4 + l) * WCH;
        const bf16* W2T = wts + (size_t)(6 + l) * WCH;
        const float* b1v = a1b + (size_t)l * 4 * D;
        const float* b2v = a2b + (size_t)l * 4 * D;

        // self-attention
        gemm_bf16<64, 64><<<dim3(24, 32), 256, 0, stream>>>(xb16, A1T, b1v, nullptr, qkv16, D, QKVLD, 0);
        vt_kernel<<<dim3(32, 8), 256, 0, stream>>>(qkv16, vt16);
        attn_mfma2<1><<<dim3(128, 8), 64, 0, stream>>>(qkv16, vt16, att16);
        gemm_bf16<64, 64><<<dim3(8, 32), 256, 0, stream>>>(att16, A1T + 3 * DD, b1v + 3 * D, ao, nullptr, D, D, 0);
        add_ln_kernel<<<S, 128, 0, stream>>>(xb, ao, lng + (size_t)(l * 3 + 0) * D, lnb + (size_t)(l * 3 + 0) * D, xb, xb16);

        // cross-attention
        gemm_bf16<64, 64><<<dim3(8, 32), 256, 0, stream>>>(xb16, A2T, b2v, nullptr, qkv16, D, QKVLD, 0);
        gemm_bf16<64, 64><<<dim3(16, 32), 256, 0, stream>>>(enc16, A2T + DD, b2v + D, nullptr, qkv16 + D, D, QKVLD, 0);
        vt_kernel<<<dim3(32, 8), 256, 0, stream>>>(qkv16, vt16);
        attn_mfma2<0><<<dim3(128, 8), 64, 0, stream>>>(qkv16, vt16, att16);
        gemm_bf16<64, 64><<<dim3(8, 32), 256, 0, stream>>>(att16, A2T + 3 * DD, b2v + 3 * D, ao, nullptr, D, D, 0);
        add_ln_kernel<<<S, 128, 0, stream>>>(xb, ao, lng + (size_t)(l * 3 + 1) * D, lnb + (size_t)(l * 3 + 1) * D, xb, xb16);

        // FFN
        gemm_bf16<128, 128><<<dim3(16, 16), 256, 0, stream>>>(xb16, W1T, fb1 + (size_t)l * F, nullptr, ffh16, D, F, 1);
        gemm_bf16<64, 64><<<dim3(8, 32), 256, 0, stream>>>(ffh16, W2T, fb2 + (size_t)l * D, ao, nullptr, F, D, 0);
        float* dstF = (l == NLAYER - 1) ? out : xb;
        bf16* dstB = (l == NLAYER - 1) ? nullptr : xb16;
        add_ln_kernel<<<S, 128, 0, stream>>>(xb, ao, lng + (size_t)(l * 3 + 2) * D, lnb + (size_t)(l * 3 + 2) * D, dstF, dstB);
    }
}

// Round 4
// 439.854 us; speedup vs baseline: 12.0205x; 1.4685x over previous
//
#include <hip/hip_runtime.h>
#include <hip/hip_bf16.h>
#include <math.h>

#define S 2048
#define D 512
#define H 8
#define DH 64
#define F 2048
#define NLAYER 2
#define QKVLD 1536   // qkv buffer row stride (3*D)

typedef __attribute__((ext_vector_type(8))) short bf16x8;
typedef __attribute__((ext_vector_type(4))) float f32x4;
typedef __hip_bfloat16 bf16;

typedef __attribute__((address_space(3))) unsigned int lds_u32;
typedef __attribute__((address_space(1))) const unsigned int glb_u32;

__device__ __forceinline__ void gld16(const void* g, void* l) {
    __builtin_amdgcn_global_load_lds((glb_u32*)g, (lds_u32*)l, 16, 0, 0);
}

// ---------------- positional encoding add (fp32 + bf16 mirror) ----------------
__global__ void pos_add_kernel(const float* __restrict__ x, float* __restrict__ outF,
                               bf16* __restrict__ outB) {
    int idx = blockIdx.x * blockDim.x + threadIdx.x;
    if (idx >= S * D) return;
    int s = idx / D;
    int j = idx % D;
    int jj = (j < D / 2) ? j : j - D / 2;
    float rate = expf(-(float)jj * (logf(10000.0f) / (float)(D / 2)));
    float ang = (float)s * rate;
    float pe = (j < D / 2) ? sinf(ang) : cosf(ang);
    float v = x[idx] + pe;
    outF[idx] = v;
    outB[idx] = __float2bfloat16(v);
}

// ---------------- fp32 -> bf16 convert ----------------
__global__ void cvt_kernel(const float* __restrict__ in, bf16* __restrict__ out, int n) {
    int idx = blockIdx.x * blockDim.x + threadIdx.x;
    if (idx < n) out[idx] = __float2bfloat16(in[idx]);
}

// ---------------- batched transpose + convert ----------------
__global__ __launch_bounds__(256)
void transpose_cvt_b(const float* __restrict__ in, bf16* __restrict__ out, int R, int C,
                     size_t inStride, size_t outL, size_t outM, int mpl)
{
    __shared__ float t[64][65];
    const int z = blockIdx.z;
    const float* src = in + (size_t)z * inStride;
    bf16* dst = out + (size_t)(z / mpl) * outL + (size_t)(z % mpl) * outM;
    const int rb = blockIdx.x * 64, cb = blockIdx.y * 64;
    for (int i = threadIdx.x; i < 4096; i += 256) {
        int r = i >> 6, c = i & 63;
        t[r][c] = src[(size_t)(rb + r) * C + cb + c];
    }
    __syncthreads();
    for (int i = threadIdx.x; i < 4096; i += 256) {
        int r = i >> 6, c = i & 63;
        dst[(size_t)(cb + r) * R + rb + c] = __float2bfloat16(t[c][r]);
    }
}

// ---------------- V transpose: Vt[d][s] = QKV[s][1024 + d] ----------------
__global__ __launch_bounds__(256)
void vt_kernel(const bf16* __restrict__ qkv, bf16* __restrict__ vt)
{
    __shared__ short t[64][72];
    const int sb = blockIdx.x * 64;   // seq tile
    const int db = blockIdx.y * 64;   // d tile (0..511 across heads)
    for (int i = threadIdx.x; i < 512; i += 256) {
        int r = i >> 3, c8 = (i & 7) * 8;
        *(bf16x8*)&t[r][c8] = *(const bf16x8*)(qkv + (size_t)(sb + r) * QKVLD + 2 * D + db + c8);
    }
    __syncthreads();
    for (int i = threadIdx.x; i < 512; i += 256) {
        int d = i >> 3, s8 = (i & 7) * 8;
        bf16x8 v;
#pragma unroll
        for (int j = 0; j < 8; ++j) v[j] = t[s8 + j][d];
        *(bf16x8*)(vt + (size_t)(db + d) * S + sb + s8) = v;
    }
}

// ---------------- bf16 MFMA GEMM: out = A[M,K] @ Bt[N,K]^T + bias ----------------
template<int BM, int BN>
__global__ __launch_bounds__(256)
void gemm_bf16(const bf16* __restrict__ A, const bf16* __restrict__ Bt,
               const float* __restrict__ bias, float* __restrict__ outF,
               bf16* __restrict__ outB, int K, int ldc, int relu)
{
    constexpr int MI = BM / 32, NJ = BN / 32;
    __shared__ char lds[(BM + BN) * 64];
    const int tid = threadIdx.x;
    const int w = tid >> 6, l = tid & 63;
    const int l15 = l & 15, l4 = l >> 4;
    const int bm = blockIdx.y * BM, bn = blockIdx.x * BN;
    const int wr = (w >> 1) * (BM / 2), wc = (w & 1) * (BN / 2);

    f32x4 acc[MI][NJ] = {};
    const int sp = l & 3;          // physical 16B slot within 64B row

    for (int k0 = 0; k0 < K; k0 += 32) {
#pragma unroll
        for (int i = 0; i < BM / 64; ++i) {
            int row = w * (BM / 4) + i * 16 + (l >> 2);
            int sl = (sp ^ ((row >> 1) & 3)) * 8;
            gld16(A + (size_t)(bm + row) * K + k0 + sl, lds + (w * (BM / 4) + i * 16) * 64);
        }
#pragma unroll
        for (int i = 0; i < BN / 64; ++i) {
            int row = w * (BN / 4) + i * 16 + (l >> 2);
            int sl = (sp ^ ((row >> 1) & 3)) * 8;
            gld16(Bt + (size_t)(bn + row) * K + k0 + sl, lds + BM * 64 + (w * (BN / 4) + i * 16) * 64);
        }
        __syncthreads();
        bf16x8 af[MI], bfr[NJ];
#pragma unroll
        for (int i = 0; i < MI; ++i) {
            int row = wr + i * 16 + l15;
            af[i] = *(const bf16x8*)(lds + row * 64 + ((l4 ^ ((row >> 1) & 3)) << 4));
        }
#pragma unroll
        for (int j = 0; j < NJ; ++j) {
            int row = wc + j * 16 + l15;
            bfr[j] = *(const bf16x8*)(lds + BM * 64 + row * 64 + ((l4 ^ ((row >> 1) & 3)) << 4));
        }
#pragma unroll
        for (int i = 0; i < MI; ++i)
#pragma unroll
            for (int j = 0; j < NJ; ++j)
                acc[i][j] = __builtin_amdgcn_mfma_f32_16x16x32_bf16(af[i], bfr[j], acc[i][j], 0, 0, 0);
        __syncthreads();
    }

#pragma unroll
    for (int i = 0; i < MI; ++i)
#pragma unroll
        for (int j = 0; j < NJ; ++j)
#pragma unroll
            for (int q = 0; q < 4; ++q) {
                int row = bm + wr + i * 16 + l4 * 4 + q;
                int col = bn + wc + j * 16 + l15;
                float v = acc[i][j][q] + bias[col];
                if (relu) v = fmaxf(v, 0.f);
                if (outF) outF[(size_t)row * ldc + col] = v;
                if (outB) outB[(size_t)row * ldc + col] = __float2bfloat16(v);
            }
}

// ---------------- split-key MFMA flash attention with in-block merge ----------
// Block = 4 waves, one (head, q-tile of 16). Wave w handles 64-key chunks
// c ≡ w (mod 4). Swapped QK^T (mfma(K,Q)): lane l holds P for q = l&15.
// Final flash-decoding merge of the 4 partials via LDS, one barrier.
// Grid: (H, S/16)  -> x = head (XCD locality on K/V), y = q-tile.
template<int CAUSAL>
__global__ __launch_bounds__(256)
void attn_mfma3(const bf16* __restrict__ QKV, const bf16* __restrict__ Vt,
                bf16* __restrict__ O)
{
    // [0, 8192): per-wave P tiles (2048 each, XOR-swizzled)
    // [8192, 26112): merge region, 4 x 4480 (o 16x68 words + m 16 + l 16)
    __shared__ char lds[26112];
    const int tid = threadIdx.x;
    const int w = tid >> 6, l = tid & 63;
    const int l15 = l & 15, l4 = l >> 4;
    const int h = blockIdx.x, qt = blockIdx.y;
    const int qbase = qt * 16;
    const int qr = qbase + l15;
    char* plds = lds + w * 2048;

    bf16x8 aq[2];
#pragma unroll
    for (int s = 0; s < 2; ++s)
        aq[s] = *(const bf16x8*)(QKV + (size_t)(qbase + l15) * QKVLD + h * DH + s * 32 + l4 * 8);

    f32x4 o[4] = {};              // o[dt]: q = l4*4+reg, d = dt*16+l15
    float mrun = -1e30f, lrun = 0.f;

    const int cdiag = qt >> 2;                    // causal diagonal chunk
    const int cmax = CAUSAL ? cdiag : (S / 64 - 1);
    for (int c = w; c <= cmax; c += 4) {
        const int kbase = c * 64;

        // S^T tiles: rows=keys, cols=q
        f32x4 st[4];
#pragma unroll
        for (int t = 0; t < 4; ++t) {
            f32x4 sacc = {0.f, 0.f, 0.f, 0.f};
#pragma unroll
            for (int s = 0; s < 2; ++s) {
                bf16x8 kf = *(const bf16x8*)(QKV + (size_t)(kbase + t * 16 + l15) * QKVLD
                                             + D + h * DH + s * 32 + l4 * 8);
                sacc = __builtin_amdgcn_mfma_f32_16x16x32_bf16(kf, aq[s], sacc, 0, 0, 0);
            }
            st[t] = sacc;
        }

        // per-lane softmax over the 16 held values (all for q = l15)
        float p[4][4];
        float mx = -1e30f;
#pragma unroll
        for (int t = 0; t < 4; ++t)
#pragma unroll
            for (int r = 0; r < 4; ++r) {
                float v = st[t][r] * 0.125f;
                if (CAUSAL && c == cdiag) {
                    int key = kbase + t * 16 + l4 * 4 + r;
                    if (key > qr) v = -1e30f;
                }
                p[t][r] = v;
                mx = fmaxf(mx, v);
            }
        mx = fmaxf(mx, __shfl_xor(mx, 16));
        mx = fmaxf(mx, __shfl_xor(mx, 32));
        float mnew = fmaxf(mrun, mx);
        float scl = __expf(mrun - mnew);
        mrun = mnew;

        float ps = 0.f;
#pragma unroll
        for (int t = 0; t < 4; ++t) {
            float e0 = __expf(p[t][0] - mnew);
            float e1 = __expf(p[t][1] - mnew);
            float e2 = __expf(p[t][2] - mnew);
            float e3 = __expf(p[t][3] - mnew);
            ps += (e0 + e1) + (e2 + e3);
            unsigned int lo = (unsigned int)(unsigned short)__builtin_bit_cast(short, __float2bfloat16(e0))
                            | ((unsigned int)(unsigned short)__builtin_bit_cast(short, __float2bfloat16(e1)) << 16);
            unsigned int hi = (unsigned int)(unsigned short)__builtin_bit_cast(short, __float2bfloat16(e2))
                            | ((unsigned int)(unsigned short)__builtin_bit_cast(short, __float2bfloat16(e3)) << 16);
            uint2 pk; pk.x = lo; pk.y = hi;
            int byte = (l15 * 128 + t * 32 + l4 * 8) ^ ((l15 & 7) << 4);
            *(uint2*)(plds + byte) = pk;
        }
        ps += __shfl_xor(ps, 16);
        ps += __shfl_xor(ps, 32);
        lrun = lrun * scl + ps;

        // rescale o: row q' = l4*4+j needs scl from lane (l&48)|q'
#pragma unroll
        for (int j = 0; j < 4; ++j) {
            float sj = __shfl(scl, (l & 48) | (l4 * 4 + j));
#pragma unroll
            for (int dt = 0; dt < 4; ++dt) o[dt][j] *= sj;
        }

        // PV: A-frag from plds (row=q=l15, k=key), B-frag from Vt (contiguous)
#pragma unroll
        for (int dt = 0; dt < 4; ++dt) {
#pragma unroll
            for (int s = 0; s < 2; ++s) {
                int byte = (l15 * 128 + s * 64 + l4 * 16) ^ ((l15 & 7) << 4);
                bf16x8 pf = *(const bf16x8*)(plds + byte);
                bf16x8 vf = *(const bf16x8*)(Vt + (size_t)(h * DH + dt * 16 + l15) * S
                                             + kbase + s * 32 + l4 * 8);
                o[dt] = __builtin_amdgcn_mfma_f32_16x16x32_bf16(pf, vf, o[dt], 0, 0, 0);
            }
        }
    }

    // ---- store partials ----
    const int wb = 8192 + w * 4480;
#pragma unroll
    for (int dt = 0; dt < 4; ++dt)
#pragma unroll
        for (int j = 0; j < 4; ++j)
            *(float*)(lds + wb + (((l4 * 4 + j) * 68) + dt * 16 + l15) * 4) = o[dt][j];
    if (l4 == 0) {
        *(float*)(lds + wb + 4352 + l15 * 4) = mrun;
        *(float*)(lds + wb + 4416 + l15 * 4) = lrun;
    }
    __syncthreads();

    // ---- merge 4 partials: thread t -> q = t>>4, d0 = (t&15)*4 ----
    const int q = tid >> 4, d0 = (tid & 15) * 4;
    float mv[4], lv[4];
    float mt = -1e30f;
#pragma unroll
    for (int ww = 0; ww < 4; ++ww) {
        mv[ww] = *(float*)(lds + 8192 + ww * 4480 + 4352 + q * 4);
        lv[ww] = *(float*)(lds + 8192 + ww * 4480 + 4416 + q * 4);
        mt = fmaxf(mt, mv[ww]);
    }
    float lt = 0.f;
    float acc0 = 0.f, acc1 = 0.f, acc2 = 0.f, acc3 = 0.f;
#pragma unroll
    for (int ww = 0; ww < 4; ++ww) {
        float f = __expf(mv[ww] - mt);
        lt += f * lv[ww];
        float4 ov = *(const float4*)(lds + 8192 + ww * 4480 + (q * 68 + d0) * 4);
        acc0 += f * ov.x; acc1 += f * ov.y; acc2 += f * ov.z; acc3 += f * ov.w;
    }
    float inv = 1.f / lt;
    bf16* op = O + (size_t)(qbase + q) * D + h * DH + d0;
    op[0] = __float2bfloat16(acc0 * inv);
    op[1] = __float2bfloat16(acc1 * inv);
    op[2] = __float2bfloat16(acc2 * inv);
    op[3] = __float2bfloat16(acc3 * inv);
}

// ---------------- residual add + layernorm (fp32, optional bf16 mirror) ----------------
__global__ __launch_bounds__(128)
void add_ln_kernel(const float* __restrict__ a, const float* __restrict__ b,
                   const float* __restrict__ g, const float* __restrict__ beta,
                   float* __restrict__ outF, bf16* __restrict__ outB)
{
    const int row = blockIdx.x;
    const int tid = threadIdx.x;
    float4 av = *(const float4*)&a[(size_t)row * D + tid * 4];
    float4 bv = *(const float4*)&b[(size_t)row * D + tid * 4];
    float4 s;
    s.x = av.x + bv.x; s.y = av.y + bv.y; s.z = av.z + bv.z; s.w = av.w + bv.w;
    float sum = s.x + s.y + s.z + s.w;
    float sq = s.x * s.x + s.y * s.y + s.z * s.z + s.w * s.w;
#pragma unroll
    for (int off = 32; off > 0; off >>= 1) {
        sum += __shfl_xor(sum, off);
        sq  += __shfl_xor(sq, off);
    }
    __shared__ float red[4];
    if ((tid & 63) == 0) { red[(tid >> 6) * 2] = sum; red[(tid >> 6) * 2 + 1] = sq; }
    __syncthreads();
    sum = red[0] + red[2];
    sq  = red[1] + red[3];
    float mu = sum / (float)D;
    float var = sq / (float)D - mu * mu;
    float rs = rsqrtf(var + 1e-6f);
    float4 gv = *(const float4*)&g[tid * 4];
    float4 bt = *(const float4*)&beta[tid * 4];
    float4 o;
    o.x = (s.x - mu) * rs * gv.x + bt.x;
    o.y = (s.y - mu) * rs * gv.y + bt.y;
    o.z = (s.z - mu) * rs * gv.z + bt.z;
    o.w = (s.w - mu) * rs * gv.w + bt.w;
    *(float4*)&outF[(size_t)row * D + tid * 4] = o;
    if (outB) {
        outB[(size_t)row * D + tid * 4 + 0] = __float2bfloat16(o.x);
        outB[(size_t)row * D + tid * 4 + 1] = __float2bfloat16(o.y);
        outB[(size_t)row * D + tid * 4 + 2] = __float2bfloat16(o.z);
        outB[(size_t)row * D + tid * 4 + 3] = __float2bfloat16(o.w);
    }
}

extern "C" void kernel_launch(void* const* d_in, const int* in_sizes, int n_in,
                              void* d_out, int out_size, void* d_ws, size_t ws_size,
                              hipStream_t stream)
{
    const float* x   = (const float*)d_in[0];
    const float* enc = (const float*)d_in[1];
    const float* a1w = (const float*)d_in[2];
    const float* a1b = (const float*)d_in[3];
    const float* a2w = (const float*)d_in[4];
    const float* a2b = (const float*)d_in[5];
    const float* fw1 = (const float*)d_in[6];
    const float* fb1 = (const float*)d_in[7];
    const float* fw2 = (const float*)d_in[8];
    const float* fb2 = (const float*)d_in[9];
    const float* lng = (const float*)d_in[10];
    const float* lnb = (const float*)d_in[11];
    float* out = (float*)d_out;

    char* wsb = (char*)d_ws;
    float* xb   = (float*)(wsb);                       // 4 MB
    float* ao   = (float*)(wsb + ((size_t)4 << 20));   // 4 MB
    bf16* xb16  = (bf16*)(wsb + ((size_t)8 << 20));    // 2 MB
    bf16* enc16 = (bf16*)(wsb + ((size_t)10 << 20));   // 2 MB
    bf16* att16 = (bf16*)(wsb + ((size_t)12 << 20));   // 2 MB
    bf16* qkv16 = (bf16*)(wsb + ((size_t)14 << 20));   // 6 MB [S][1536]
    bf16* vt16  = (bf16*)(wsb + ((size_t)20 << 20));   // 2 MB [512][S]
    bf16* ffh16 = qkv16;                               // 8 MB (overlaps vt16; disjoint lifetime)
    bf16* wts   = (bf16*)(wsb + ((size_t)22 << 20));   // 16 MB
    const size_t WCH = 1048576;
    const size_t DD = (size_t)D * D, DF = (size_t)D * F;

    // ---- weight prep (batched): transpose + bf16 ----
    transpose_cvt_b<<<dim3(8, 8, 8), 256, 0, stream>>>(a1w, wts,            D, D, DD, WCH, DD, 4);
    transpose_cvt_b<<<dim3(8, 8, 8), 256, 0, stream>>>(a2w, wts + 2 * WCH,  D, D, DD, WCH, DD, 4);
    transpose_cvt_b<<<dim3(8, 32, 2), 256, 0, stream>>>(fw1, wts + 4 * WCH, D, F, DF, WCH, 0, 1);
    transpose_cvt_b<<<dim3(32, 8, 2), 256, 0, stream>>>(fw2, wts + 6 * WCH, F, D, DF, WCH, 0, 1);
    cvt_kernel<<<(S * D + 255) / 256, 256, 0, stream>>>(enc, enc16, S * D);
    pos_add_kernel<<<(S * D + 255) / 256, 256, 0, stream>>>(x, xb, xb16);

    for (int l = 0; l < NLAYER; ++l) {
        const bf16* A1T = wts + (size_t)(0 + l) * WCH;
        const bf16* A2T = wts + (size_t)(2 + l) * WCH;
        const bf16* W1T = wts + (size_t)(4 + l) * WCH;
        const bf16* W2T = wts + (size_t)(6 + l) * WCH;
        const float* b1v = a1b + (size_t)l * 4 * D;
        const float* b2v = a2b + (size_t)l * 4 * D;

        // self-attention
        gemm_bf16<64, 64><<<dim3(24, 32), 256, 0, stream>>>(xb16, A1T, b1v, nullptr, qkv16, D, QKVLD, 0);
        vt_kernel<<<dim3(32, 8), 256, 0, stream>>>(qkv16, vt16);
        attn_mfma3<1><<<dim3(H, S / 16), 256, 0, stream>>>(qkv16, vt16, att16);
        gemm_bf16<64, 64><<<dim3(8, 32), 256, 0, stream>>>(att16, A1T + 3 * DD, b1v + 3 * D, ao, nullptr, D, D, 0);
        add_ln_kernel<<<S, 128, 0, stream>>>(xb, ao, lng + (size_t)(l * 3 + 0) * D, lnb + (size_t)(l * 3 + 0) * D, xb, xb16);

        // cross-attention
        gemm_bf16<64, 64><<<dim3(8, 32), 256, 0, stream>>>(xb16, A2T, b2v, nullptr, qkv16, D, QKVLD, 0);
        gemm_bf16<64, 64><<<dim3(16, 32), 256, 0, stream>>>(enc16, A2T + DD, b2v + D, nullptr, qkv16 + D, D, QKVLD, 0);
        vt_kernel<<<dim3(32, 8), 256, 0, stream>>>(qkv16, vt16);
        attn_mfma3<0><<<dim3(H, S / 16), 256, 0, stream>>>(qkv16, vt16, att16);
        gemm_bf16<64, 64><<<dim3(8, 32), 256, 0, stream>>>(att16, A2T + 3 * DD, b2v + 3 * D, ao, nullptr, D, D, 0);
        add_ln_kernel<<<S, 128, 0, stream>>>(xb, ao, lng + (size_t)(l * 3 + 1) * D, lnb + (size_t)(l * 3 + 1) * D, xb, xb16);

        // FFN
        gemm_bf16<128, 128><<<dim3(16, 16), 256, 0, stream>>>(xb16, W1T, fb1 + (size_t)l * F, nullptr, ffh16, D, F, 1);
        gemm_bf16<64, 64><<<dim3(8, 32), 256, 0, stream>>>(ffh16, W2T, fb2 + (size_t)l * D, ao, nullptr, F, D, 0);
        float* dstF = (l == NLAYER - 1) ? out : xb;
        bf16* dstB = (l == NLAYER - 1) ? nullptr : xb16;
        add_ln_kernel<<<S, 128, 0, stream>>>(xb, ao, lng + (size_t)(l * 3 + 2) * D, lnb + (size_t)(l * 3 + 2) * D, dstF, dstB);
    }
}